// Round 1
// 199.566 us; speedup vs baseline: 1.0424x; 1.0424x over previous
//
#include <hip/hip_runtime.h>

constexpr int H = 2048, W = 2048, HW = H * W, MASK = 2047;
constexpr float TEMP = 0.1f;
constexpr float EPS = 1e-8f;
constexpr float SQ2 = 0.70710678118654752440f;
constexpr int NACC = 128;   // accumulator slots per sum, one cache line each

// ---------------------------------------------------------------------------
// Fused kernel, 16x32 interior tile per 512-thread block.
// Round 8 (from 82us k_main, VALU 54%, HBM 20%):
//  * phase 2's 5 scattered global loads/cell (mass, fx, fy, mx, my) + the
//    wrap-masked 2D address math are replaced by LDS reads: phase 1 already
//    holds m/fx/fy in registers for the ring domain and now stores them
//    (M/FXY), and loads momentum pairs (PM) reusing its computed index.
//  * MS/PMX/PMY ds_writes collapse into an in-place float2 PM update;
//    phase 3 reads {pmx,pmy} as one b64 (27 LDS reads, was 36).
//  * unified 18x36 staged layout (s = sy*36+sx+?): PR is [9][648] so one
//    index serves PR/M/PM/FXY in phases 2 and 3.
//  * every float op (conv / force / velocity divide / logits / exp /
//    softmax / gather fmaf order) is unchanged on unchanged values:
//    bit-identical to the passing 0.0156 draw. LDS 32.8->38.8 KB, still
//    4 blocks/CU (32 waves, occupancy cap).
// ---------------------------------------------------------------------------
__global__ __launch_bounds__(512) void k_main(
    const float* __restrict__ mass, const float* __restrict__ mom,
    const float* __restrict__ force, const float* __restrict__ A,
    const float* __restrict__ ker,
    float* __restrict__ out,            // [nm | mom_x | mom_y | f_x | f_y]
    double* __restrict__ acc)           // [NACC*8 for mass | NACC*8 for nm]
{
    __shared__ __align__(16) float XS[20 * 40];   // halo y:-2..17, x:-4..35
    __shared__ __align__(16) float M[648];        // staged 18x36: y:-1..16, x:-2..33
    __shared__ float2 PM[648];                    // {mx,my} -> {pmx,pmy} in place
    __shared__ float2 FXY[648];                   // {fx,fy}
    __shared__ float  PR[9][648];
    __shared__ float  KS[36];
    __shared__ float  wsum0[8], wsum1[8];

    const int tid = threadIdx.x;
    // XCD-aware tile mapping: xcd = b&7 owns 16 consecutive tile rows
    const int b = blockIdx.x;                      // 8192 blocks: 128y x 64x
    const int xcd = b & 7, r = b >> 3;
    const int by = (xcd << 4) | (r >> 6), bx = r & 63;
    const int gx0 = bx << 5, gy0 = by << 4;

    if (tid < 36) KS[tid] = ker[tid];

    // ---- phase 1: stage X on 20x40 halo, float2 loads; ring cells also
    //      stage m/f (register reuse, no extra loads) and momentum ----
    if (tid < 400) {
        const int py = tid / 20, px2 = (tid - py * 20) * 2;   // cols 0..38
        const int gy = (gy0 + py - 2) & MASK;
        const int gxp = (gx0 + px2 - 4) & MASK;               // even, no row cross
        const int idx = gy * W + gxp;
        const float2 m2 = *(const float2*)(mass + idx);
        const float2 a2 = *(const float2*)(A + idx);
        const float2 fx2 = *(const float2*)(force + idx);
        const float2 fy2 = *(const float2*)(force + HW + idx);
        float x0 = __fadd_rn(__fmul_rn(a2.x, m2.x),
            __fsqrt_rn(__fadd_rn(__fmul_rn(fx2.x, fx2.x), __fmul_rn(fy2.x, fy2.x))));
        float x1 = __fadd_rn(__fmul_rn(a2.y, m2.y),
            __fsqrt_rn(__fadd_rn(__fmul_rn(fy2.y, fy2.y), __fmul_rn(fx2.y, fx2.y))));
        // NOTE: keep operand order of the fx*fx + fy*fy sum identical to before:
        x1 = __fadd_rn(__fmul_rn(a2.y, m2.y),
            __fsqrt_rn(__fadd_rn(__fmul_rn(fx2.y, fx2.y), __fmul_rn(fy2.y, fy2.y))));
        *(float2*)&XS[py * 40 + px2] = make_float2(x0, x1);
        // staged ring domain: rows gy0-1..16 (py 1..18), cols gx0-2..33 (px2 2..36)
        if (py >= 1 && py <= 18 && px2 >= 2 && px2 <= 36) {
            const int s = (py - 1) * 36 + (px2 - 2);          // even
            *(float2*)&M[s] = m2;
            FXY[s]     = make_float2(fx2.x, fy2.x);
            FXY[s + 1] = make_float2(fx2.y, fy2.y);
            const float2 mx2 = *(const float2*)(mom + idx);
            const float2 my2 = *(const float2*)(mom + HW + idx);
            PM[s]     = make_float2(mx2.x, my2.x);
            PM[s + 1] = make_float2(mx2.y, my2.y);
        }
    }
    __syncthreads();

    float ksum = 0.f;
#pragma unroll
    for (int i = 0; i < 36; ++i) ksum = __fadd_rn(ksum, fabsf(KS[i]));
    const float kc = 1.0f / ksum;

    // ---- phase 2: per 18x34 ring cell, all operands from LDS ----
    auto cell = [&](int t) {
        const int ly = t / 34, lx = t - ly * 34;
        const int s = ly * 36 + lx + 1;                       // staged index
        const float m   = M[s];
        const float2 f2 = FXY[s];
        const float2 q2 = PM[s];

        float nf0 = 0.f, nf1 = 0.f, nf2 = 0.f, nf3 = 0.f;
#pragma unroll
        for (int ky = 0; ky < 3; ++ky)
#pragma unroll
            for (int kx = 0; kx < 3; ++kx) {
                const float x = XS[(ly + ky) * 40 + lx + kx + 2];
                const int j = ky * 3 + kx;
                nf0 = __fadd_rn(nf0, __fmul_rn(KS[j],      x));
                nf1 = __fadd_rn(nf1, __fmul_rn(KS[9 + j],  x));
                nf2 = __fadd_rn(nf2, __fmul_rn(KS[18 + j], x));
                nf3 = __fadd_rn(nf3, __fmul_rn(KS[27 + j], x));
            }
        const float nfx = __fadd_rn(nf0, nf1);                     // sum
        const float nfy = __fmul_rn(__fadd_rn(nf2, nf3), 0.5f);    // mean
        const float fnx = __fadd_rn(f2.x, __fmul_rn(__fsub_rn(nfx, f2.x), kc));
        const float fny = __fadd_rn(f2.y, __fmul_rn(__fsub_rn(nfy, f2.y), kc));
        const bool dead = m < EPS;
        const float pmx = dead ? 0.f : __fadd_rn(q2.x, fnx);       // DT = 1
        const float pmy = dead ? 0.f : __fadd_rn(q2.y, fny);
        PM[s] = make_float2(pmx, pmy);                             // in place
        const float vx = dead ? 0.f : pmx / m;
        const float vy = dead ? 0.f : pmy / m;

        // logits, bit-exact to np einsum (sign-symmetric IEEE rounding)
        const float p = __fmul_rn(SQ2, vx), q = __fmul_rn(SQ2, vy);
        const float l0 = __fmul_rn(__fadd_rn(p, q), TEMP);   // dir ( s, s)
        const float l1 = __fmul_rn(vy, TEMP);                // dir ( 0, 1)
        const float l2 = __fmul_rn(__fsub_rn(q, p), TEMP);   // dir (-s, s)
        const float l3 = __fmul_rn(vx, TEMP);                // dir ( 1, 0)
        const float lmax = fmaxf(fmaxf(fabsf(l0), fabsf(l1)),
                                 fmaxf(fabsf(l2), fmaxf(fabsf(l3), 0.f)));
        const float l[9] = {l0, l1, l2, l3, 0.f, -l3, -l2, -l1, -l0};
        float e[9], esum = 0.f;
#pragma unroll
        for (int d = 0; d < 9; ++d) {
            e[d] = __expf(__fsub_rn(l[d], lmax));   // native v_exp_f32
            esum = __fadd_rn(esum, e[d]);
        }
        const float inv = 1.0f / esum;
#pragma unroll
        for (int d = 0; d < 9; ++d) PR[d][s] = __fmul_rn(e[d], inv);

        if (ly >= 1 && ly <= 16 && lx >= 1 && lx <= 32) {          // interior
            const int gidx = (gy0 + ly - 1) * W + gx0 + lx - 1;
            out[3 * HW + gidx] = fnx;
            out[4 * HW + gidx] = fny;
        }
    };
    cell(tid);
    if (tid < 100) cell(tid + 512);
    __syncthreads();

    // ---- phase 3: gather for 16x32 interior (fmaf safe: not amplified) ----
    const int tx = tid & 31, ty = tid >> 5;
    float nm = 0.f, omx = 0.f, omy = 0.f;
#pragma unroll
    for (int d = 0; d < 9; ++d) {
        const int dy = 1 - d / 3, dx = 1 - d % 3;                  // MOVES shift
        const int sn = (ty + 1 + dy) * 36 + (tx + 1 + dx) + 1;
        const float pp = PR[d][sn];
        const float2 pm2 = PM[sn];
        nm  = fmaf(M[sn],  pp, nm);
        omx = fmaf(pm2.x, pp, omx);
        omy = fmaf(pm2.y, pp, omy);
    }
    const int gidx = (gy0 + ty) * W + gx0 + tx;
    out[gidx]          = nm;                                       // unnormalized
    out[HW + gidx]     = omx;
    out[2 * HW + gidx] = omy;

    // ---- block reductions -> line-spread f64 accumulators ----
    float s0 = M[(ty + 1) * 36 + tx + 2];                          // own mass
    float s1 = nm;
#pragma unroll
    for (int off = 32; off > 0; off >>= 1) {
        s0 += __shfl_down(s0, off);
        s1 += __shfl_down(s1, off);
    }
    if ((tid & 63) == 0) { wsum0[tid >> 6] = s0; wsum1[tid >> 6] = s1; }
    __syncthreads();
    if (tid == 0) {
        float t0 = 0.f, t1 = 0.f;
#pragma unroll
        for (int i = 0; i < 8; ++i) { t0 += wsum0[i]; t1 += wsum1[i]; }
        const int slot = (blockIdx.x & (NACC - 1)) * 8;            // own line
        atomicAdd(acc + slot,            (double)t0);
        atomicAdd(acc + NACC * 8 + slot, (double)t1);
    }
}

// ---------------------------------------------------------------------------
// Rescale: reduce the 2*NACC partials in-register (lane-parallel + shuffle),
// then new_mass = mass_tot * new_mass / sum(new_mass), in place, float4.
// ---------------------------------------------------------------------------
__global__ __launch_bounds__(256) void k_norm(
    float* __restrict__ nm, const double* __restrict__ acc)
{
    const int lane = threadIdx.x & 63;
    double s0 = 0.0, s1 = 0.0;
#pragma unroll
    for (int i = 0; i < NACC / 64; ++i) {                // 2 slots per lane
        const int slot = (lane + i * 64) * 8;
        s0 += acc[slot];
        s1 += acc[NACC * 8 + slot];
    }
#pragma unroll
    for (int off = 32; off > 0; off >>= 1) {
        s0 += __shfl_down(s0, off);
        s1 += __shfl_down(s1, off);
    }
    const float mt  = (float)__shfl(s0, 0);
    const float snm = (float)__shfl(s1, 0);

    const int i = (blockIdx.x * 256 + threadIdx.x) * 4;
    float4 v = *(float4*)(nm + i);
    v.x = __fmul_rn(mt, v.x) / snm;
    v.y = __fmul_rn(mt, v.y) / snm;
    v.z = __fmul_rn(mt, v.z) / snm;
    v.w = __fmul_rn(mt, v.w) / snm;
    *(float4*)(nm + i) = v;
}

extern "C" void kernel_launch(void* const* d_in, const int* in_sizes, int n_in,
                              void* d_out, int out_size, void* d_ws, size_t ws_size,
                              hipStream_t stream)
{
    const float* mass  = (const float*)d_in[0];
    const float* mom   = (const float*)d_in[1];
    const float* force = (const float*)d_in[2];
    const float* A     = (const float*)d_in[3];
    const float* ker   = (const float*)d_in[4];
    float* out = (float*)d_out;

    double* acc = (double*)d_ws;                  // 2 * NACC * 8 doubles = 16 KiB
    hipMemsetAsync(acc, 0, 2 * NACC * 8 * sizeof(double), stream);

    k_main<<<dim3(8192), dim3(512), 0, stream>>>(mass, mom, force, A, ker,
                                                 out, acc);
    k_norm<<<dim3(HW / 1024), dim3(256), 0, stream>>>(out, acc);
}

// Round 2
// 197.937 us; speedup vs baseline: 1.0509x; 1.0082x over previous
//
#include <hip/hip_runtime.h>

constexpr int H = 2048, W = 2048, HW = H * W, MASK = 2047;
constexpr float TEMP = 0.1f;
constexpr float EPS = 1e-8f;
constexpr float SQ2 = 0.70710678118654752440f;
constexpr int NACC = 128;   // accumulator slots per sum, one cache line each

// ---------------------------------------------------------------------------
// Fused kernel, 16x32 interior tile per 512-thread block.
// Round 9 (from 75us k_main, VALU 57%, conflicts 2.87M):
//  * phase-1 staging of FXY/PM fused into float4 (ds_write_b128): the two
//    b64 stores per lane sat at 16B stride (8-way bank conflict, the 1.18M
//    -> 2.87M regression of round 8); one b128 per lane is contiguous
//    1024B/wave, the natural full-BW LDS pattern.
//  * kc hoisted: all 512 threads computed the same 36-term |ker| sum
//    (~72 VALU + IEEE divide each). Now phase-1-idle tid 448 computes it
//    from global ker in the identical i=0..35 order (bit-identical) and
//    broadcasts via LDS; everyone reads it after the existing barrier.
//  * every float op of the amplified chain (conv / force / velocity divide /
//    logits / exp / softmax / gather fmaf order) unchanged on unchanged
//    values: bit-identical to the passing 0.0156 draw.
// ---------------------------------------------------------------------------
__global__ __launch_bounds__(512) void k_main(
    const float* __restrict__ mass, const float* __restrict__ mom,
    const float* __restrict__ force, const float* __restrict__ A,
    const float* __restrict__ ker,
    float* __restrict__ out,            // [nm | mom_x | mom_y | f_x | f_y]
    double* __restrict__ acc)           // [NACC*8 for mass | NACC*8 for nm]
{
    __shared__ __align__(16) float XS[20 * 40];   // halo y:-2..17, x:-4..35
    __shared__ __align__(16) float M[648];        // staged 18x36: y:-1..16, x:-2..33
    __shared__ __align__(16) float2 PM[648];      // {mx,my} -> {pmx,pmy} in place
    __shared__ __align__(16) float2 FXY[648];     // {fx,fy}
    __shared__ float  PR[9][648];
    __shared__ float  KS[36];
    __shared__ float  KC;
    __shared__ float  wsum0[8], wsum1[8];

    const int tid = threadIdx.x;
    // XCD-aware tile mapping: xcd = b&7 owns 16 consecutive tile rows
    const int b = blockIdx.x;                      // 8192 blocks: 128y x 64x
    const int xcd = b & 7, r = b >> 3;
    const int by = (xcd << 4) | (r >> 6), bx = r & 63;
    const int gx0 = bx << 5, gy0 = by << 4;

    if (tid < 36) KS[tid] = ker[tid];

    // ---- phase 1: stage X on 20x40 halo, float2 loads; ring cells also
    //      stage m/f (register reuse, no extra loads) and momentum ----
    if (tid < 400) {
        const int py = tid / 20, px2 = (tid - py * 20) * 2;   // cols 0..38
        const int gy = (gy0 + py - 2) & MASK;
        const int gxp = (gx0 + px2 - 4) & MASK;               // even, no row cross
        const int idx = gy * W + gxp;
        const float2 m2 = *(const float2*)(mass + idx);
        const float2 a2 = *(const float2*)(A + idx);
        const float2 fx2 = *(const float2*)(force + idx);
        const float2 fy2 = *(const float2*)(force + HW + idx);
        const float x0 = __fadd_rn(__fmul_rn(a2.x, m2.x),
            __fsqrt_rn(__fadd_rn(__fmul_rn(fx2.x, fx2.x), __fmul_rn(fy2.x, fy2.x))));
        const float x1 = __fadd_rn(__fmul_rn(a2.y, m2.y),
            __fsqrt_rn(__fadd_rn(__fmul_rn(fx2.y, fx2.y), __fmul_rn(fy2.y, fy2.y))));
        *(float2*)&XS[py * 40 + px2] = make_float2(x0, x1);
        // staged ring domain: rows gy0-1..16 (py 1..18), cols gx0-2..33 (px2 2..36)
        if (py >= 1 && py <= 18 && px2 >= 2 && px2 <= 36) {
            const int s = (py - 1) * 36 + (px2 - 2);          // even -> 16B aligned
            *(float2*)&M[s] = m2;
            *(float4*)&FXY[s] = make_float4(fx2.x, fy2.x, fx2.y, fy2.y);
            const float2 mx2 = *(const float2*)(mom + idx);
            const float2 my2 = *(const float2*)(mom + HW + idx);
            *(float4*)&PM[s] = make_float4(mx2.x, my2.x, mx2.y, my2.y);
        }
    } else if (tid == 448) {
        // wave-uniform kc computed once, identical op order -> bit-identical
        float ks = 0.f;
#pragma unroll
        for (int i = 0; i < 36; ++i) ks = __fadd_rn(ks, fabsf(ker[i]));
        KC = 1.0f / ks;
    }
    __syncthreads();

    const float kc = KC;

    // ---- phase 2: per 18x34 ring cell, all operands from LDS ----
    auto cell = [&](int t) {
        const int ly = t / 34, lx = t - ly * 34;
        const int s = ly * 36 + lx + 1;                       // staged index
        const float m   = M[s];
        const float2 f2 = FXY[s];
        const float2 q2 = PM[s];

        float nf0 = 0.f, nf1 = 0.f, nf2 = 0.f, nf3 = 0.f;
#pragma unroll
        for (int ky = 0; ky < 3; ++ky)
#pragma unroll
            for (int kx = 0; kx < 3; ++kx) {
                const float x = XS[(ly + ky) * 40 + lx + kx + 2];
                const int j = ky * 3 + kx;
                nf0 = __fadd_rn(nf0, __fmul_rn(KS[j],      x));
                nf1 = __fadd_rn(nf1, __fmul_rn(KS[9 + j],  x));
                nf2 = __fadd_rn(nf2, __fmul_rn(KS[18 + j], x));
                nf3 = __fadd_rn(nf3, __fmul_rn(KS[27 + j], x));
            }
        const float nfx = __fadd_rn(nf0, nf1);                     // sum
        const float nfy = __fmul_rn(__fadd_rn(nf2, nf3), 0.5f);    // mean
        const float fnx = __fadd_rn(f2.x, __fmul_rn(__fsub_rn(nfx, f2.x), kc));
        const float fny = __fadd_rn(f2.y, __fmul_rn(__fsub_rn(nfy, f2.y), kc));
        const bool dead = m < EPS;
        const float pmx = dead ? 0.f : __fadd_rn(q2.x, fnx);       // DT = 1
        const float pmy = dead ? 0.f : __fadd_rn(q2.y, fny);
        PM[s] = make_float2(pmx, pmy);                             // in place
        const float vx = dead ? 0.f : pmx / m;
        const float vy = dead ? 0.f : pmy / m;

        // logits, bit-exact to np einsum (sign-symmetric IEEE rounding)
        const float p = __fmul_rn(SQ2, vx), q = __fmul_rn(SQ2, vy);
        const float l0 = __fmul_rn(__fadd_rn(p, q), TEMP);   // dir ( s, s)
        const float l1 = __fmul_rn(vy, TEMP);                // dir ( 0, 1)
        const float l2 = __fmul_rn(__fsub_rn(q, p), TEMP);   // dir (-s, s)
        const float l3 = __fmul_rn(vx, TEMP);                // dir ( 1, 0)
        const float lmax = fmaxf(fmaxf(fabsf(l0), fabsf(l1)),
                                 fmaxf(fabsf(l2), fmaxf(fabsf(l3), 0.f)));
        const float l[9] = {l0, l1, l2, l3, 0.f, -l3, -l2, -l1, -l0};
        float e[9], esum = 0.f;
#pragma unroll
        for (int d = 0; d < 9; ++d) {
            e[d] = __expf(__fsub_rn(l[d], lmax));   // native v_exp_f32
            esum = __fadd_rn(esum, e[d]);
        }
        const float inv = 1.0f / esum;
#pragma unroll
        for (int d = 0; d < 9; ++d) PR[d][s] = __fmul_rn(e[d], inv);

        if (ly >= 1 && ly <= 16 && lx >= 1 && lx <= 32) {          // interior
            const int gidx = (gy0 + ly - 1) * W + gx0 + lx - 1;
            out[3 * HW + gidx] = fnx;
            out[4 * HW + gidx] = fny;
        }
    };
    cell(tid);
    if (tid < 100) cell(tid + 512);
    __syncthreads();

    // ---- phase 3: gather for 16x32 interior (fmaf safe: not amplified) ----
    const int tx = tid & 31, ty = tid >> 5;
    float nm = 0.f, omx = 0.f, omy = 0.f;
#pragma unroll
    for (int d = 0; d < 9; ++d) {
        const int dy = 1 - d / 3, dx = 1 - d % 3;                  // MOVES shift
        const int sn = (ty + 1 + dy) * 36 + (tx + 1 + dx) + 1;
        const float pp = PR[d][sn];
        const float2 pm2 = PM[sn];
        nm  = fmaf(M[sn],  pp, nm);
        omx = fmaf(pm2.x, pp, omx);
        omy = fmaf(pm2.y, pp, omy);
    }
    const int gidx = (gy0 + ty) * W + gx0 + tx;
    out[gidx]          = nm;                                       // unnormalized
    out[HW + gidx]     = omx;
    out[2 * HW + gidx] = omy;

    // ---- block reductions -> line-spread f64 accumulators ----
    float s0 = M[(ty + 1) * 36 + tx + 2];                          // own mass
    float s1 = nm;
#pragma unroll
    for (int off = 32; off > 0; off >>= 1) {
        s0 += __shfl_down(s0, off);
        s1 += __shfl_down(s1, off);
    }
    if ((tid & 63) == 0) { wsum0[tid >> 6] = s0; wsum1[tid >> 6] = s1; }
    __syncthreads();
    if (tid == 0) {
        float t0 = 0.f, t1 = 0.f;
#pragma unroll
        for (int i = 0; i < 8; ++i) { t0 += wsum0[i]; t1 += wsum1[i]; }
        const int slot = (blockIdx.x & (NACC - 1)) * 8;            // own line
        atomicAdd(acc + slot,            (double)t0);
        atomicAdd(acc + NACC * 8 + slot, (double)t1);
    }
}

// ---------------------------------------------------------------------------
// Rescale: reduce the 2*NACC partials in-register (lane-parallel + shuffle),
// then new_mass = mass_tot * new_mass / sum(new_mass), in place, float4.
// ---------------------------------------------------------------------------
__global__ __launch_bounds__(256) void k_norm(
    float* __restrict__ nm, const double* __restrict__ acc)
{
    const int lane = threadIdx.x & 63;
    double s0 = 0.0, s1 = 0.0;
#pragma unroll
    for (int i = 0; i < NACC / 64; ++i) {                // 2 slots per lane
        const int slot = (lane + i * 64) * 8;
        s0 += acc[slot];
        s1 += acc[NACC * 8 + slot];
    }
#pragma unroll
    for (int off = 32; off > 0; off >>= 1) {
        s0 += __shfl_down(s0, off);
        s1 += __shfl_down(s1, off);
    }
    const float mt  = (float)__shfl(s0, 0);
    const float snm = (float)__shfl(s1, 0);

    const int i = (blockIdx.x * 256 + threadIdx.x) * 4;
    float4 v = *(float4*)(nm + i);
    v.x = __fmul_rn(mt, v.x) / snm;
    v.y = __fmul_rn(mt, v.y) / snm;
    v.z = __fmul_rn(mt, v.z) / snm;
    v.w = __fmul_rn(mt, v.w) / snm;
    *(float4*)(nm + i) = v;
}

extern "C" void kernel_launch(void* const* d_in, const int* in_sizes, int n_in,
                              void* d_out, int out_size, void* d_ws, size_t ws_size,
                              hipStream_t stream)
{
    const float* mass  = (const float*)d_in[0];
    const float* mom   = (const float*)d_in[1];
    const float* force = (const float*)d_in[2];
    const float* A     = (const float*)d_in[3];
    const float* ker   = (const float*)d_in[4];
    float* out = (float*)d_out;

    double* acc = (double*)d_ws;                  // 2 * NACC * 8 doubles = 16 KiB
    hipMemsetAsync(acc, 0, 2 * NACC * 8 * sizeof(double), stream);

    k_main<<<dim3(8192), dim3(512), 0, stream>>>(mass, mom, force, A, ker,
                                                 out, acc);
    k_norm<<<dim3(HW / 1024), dim3(256), 0, stream>>>(out, acc);
}

// Round 3
// 195.395 us; speedup vs baseline: 1.0646x; 1.0130x over previous
//
#include <hip/hip_runtime.h>

constexpr int H = 2048, W = 2048, HW = H * W, MASK = 2047;
constexpr float TEMP = 0.1f;
constexpr float EPS = 1e-8f;
constexpr float SQ2 = 0.70710678118654752440f;
constexpr int NACC = 128;   // accumulator slots per sum, one cache line each

// ---------------------------------------------------------------------------
// Fused kernel, 16x32 interior tile per 512-thread block.
// Round 10 (from 73.5us k_main, VALU 52-56%, conflicts measured negligible):
//  * conv taps read directly from the uniform const-restrict global `ker`:
//    uniformity analysis lowers them to s_load -> SGPRs hoisted to the
//    prologue (hidden under phase-1 loads); each tap multiply is
//    v_mul_f32 v,s,v. Removes 36 LDS-issue + lgkm-latency exposure per
//    cell (VGPR=24 showed the compiler was re-reading KS from LDS per
//    use). KS LDS array deleted.
//  * __launch_bounds__(512,8): pins allocator to <=64 VGPR / <=100 SGPR so
//    SGPR/VGPR growth cannot silently drop the 4-blocks/CU occupancy
//    (LDS 39.8KB x4 = 159KB is the intended cap).
//  * every float op of the amplified chain (conv / force / velocity divide /
//    logits / exp / softmax / gather fmaf order) unchanged on unchanged
//    values: bit-identical to the passing 0.0156 draw.
// ---------------------------------------------------------------------------
__global__ __launch_bounds__(512, 8) void k_main(
    const float* __restrict__ mass, const float* __restrict__ mom,
    const float* __restrict__ force, const float* __restrict__ A,
    const float* __restrict__ ker,
    float* __restrict__ out,            // [nm | mom_x | mom_y | f_x | f_y]
    double* __restrict__ acc)           // [NACC*8 for mass | NACC*8 for nm]
{
    __shared__ __align__(16) float XS[20 * 40];   // halo y:-2..17, x:-4..35
    __shared__ __align__(16) float M[648];        // staged 18x36: y:-1..16, x:-2..33
    __shared__ __align__(16) float2 PM[648];      // {mx,my} -> {pmx,pmy} in place
    __shared__ __align__(16) float2 FXY[648];     // {fx,fy}
    __shared__ float  PR[9][648];
    __shared__ float  KC;
    __shared__ float  wsum0[8], wsum1[8];

    const int tid = threadIdx.x;
    // XCD-aware tile mapping: xcd = b&7 owns 16 consecutive tile rows
    const int b = blockIdx.x;                      // 8192 blocks: 128y x 64x
    const int xcd = b & 7, r = b >> 3;
    const int by = (xcd << 4) | (r >> 6), bx = r & 63;
    const int gx0 = bx << 5, gy0 = by << 4;

    // ---- phase 1: stage X on 20x40 halo, float2 loads; ring cells also
    //      stage m/f (register reuse, no extra loads) and momentum ----
    if (tid < 400) {
        const int py = tid / 20, px2 = (tid - py * 20) * 2;   // cols 0..38
        const int gy = (gy0 + py - 2) & MASK;
        const int gxp = (gx0 + px2 - 4) & MASK;               // even, no row cross
        const int idx = gy * W + gxp;
        const float2 m2 = *(const float2*)(mass + idx);
        const float2 a2 = *(const float2*)(A + idx);
        const float2 fx2 = *(const float2*)(force + idx);
        const float2 fy2 = *(const float2*)(force + HW + idx);
        const float x0 = __fadd_rn(__fmul_rn(a2.x, m2.x),
            __fsqrt_rn(__fadd_rn(__fmul_rn(fx2.x, fx2.x), __fmul_rn(fy2.x, fy2.x))));
        const float x1 = __fadd_rn(__fmul_rn(a2.y, m2.y),
            __fsqrt_rn(__fadd_rn(__fmul_rn(fx2.y, fx2.y), __fmul_rn(fy2.y, fy2.y))));
        *(float2*)&XS[py * 40 + px2] = make_float2(x0, x1);
        // staged ring domain: rows gy0-1..16 (py 1..18), cols gx0-2..33 (px2 2..36)
        if (py >= 1 && py <= 18 && px2 >= 2 && px2 <= 36) {
            const int s = (py - 1) * 36 + (px2 - 2);          // even -> 16B aligned
            *(float2*)&M[s] = m2;
            *(float4*)&FXY[s] = make_float4(fx2.x, fy2.x, fx2.y, fy2.y);
            const float2 mx2 = *(const float2*)(mom + idx);
            const float2 my2 = *(const float2*)(mom + HW + idx);
            *(float4*)&PM[s] = make_float4(mx2.x, my2.x, mx2.y, my2.y);
        }
    } else if (tid == 448) {
        // wave-uniform kc computed once, identical op order -> bit-identical
        float ks = 0.f;
#pragma unroll
        for (int i = 0; i < 36; ++i) ks = __fadd_rn(ks, fabsf(ker[i]));
        KC = 1.0f / ks;
    }
    __syncthreads();

    const float kc = KC;

    // ---- phase 2: per 18x34 ring cell, operands from LDS, taps from SGPR ----
    auto cell = [&](int t) {
        const int ly = t / 34, lx = t - ly * 34;
        const int s = ly * 36 + lx + 1;                       // staged index
        const float m   = M[s];
        const float2 f2 = FXY[s];
        const float2 q2 = PM[s];

        float nf0 = 0.f, nf1 = 0.f, nf2 = 0.f, nf3 = 0.f;
#pragma unroll
        for (int ky = 0; ky < 3; ++ky)
#pragma unroll
            for (int kx = 0; kx < 3; ++kx) {
                const float x = XS[(ly + ky) * 40 + lx + kx + 2];
                const int j = ky * 3 + kx;
                nf0 = __fadd_rn(nf0, __fmul_rn(ker[j],      x));
                nf1 = __fadd_rn(nf1, __fmul_rn(ker[9 + j],  x));
                nf2 = __fadd_rn(nf2, __fmul_rn(ker[18 + j], x));
                nf3 = __fadd_rn(nf3, __fmul_rn(ker[27 + j], x));
            }
        const float nfx = __fadd_rn(nf0, nf1);                     // sum
        const float nfy = __fmul_rn(__fadd_rn(nf2, nf3), 0.5f);    // mean
        const float fnx = __fadd_rn(f2.x, __fmul_rn(__fsub_rn(nfx, f2.x), kc));
        const float fny = __fadd_rn(f2.y, __fmul_rn(__fsub_rn(nfy, f2.y), kc));
        const bool dead = m < EPS;
        const float pmx = dead ? 0.f : __fadd_rn(q2.x, fnx);       // DT = 1
        const float pmy = dead ? 0.f : __fadd_rn(q2.y, fny);
        PM[s] = make_float2(pmx, pmy);                             // in place
        const float vx = dead ? 0.f : pmx / m;
        const float vy = dead ? 0.f : pmy / m;

        // logits, bit-exact to np einsum (sign-symmetric IEEE rounding)
        const float p = __fmul_rn(SQ2, vx), q = __fmul_rn(SQ2, vy);
        const float l0 = __fmul_rn(__fadd_rn(p, q), TEMP);   // dir ( s, s)
        const float l1 = __fmul_rn(vy, TEMP);                // dir ( 0, 1)
        const float l2 = __fmul_rn(__fsub_rn(q, p), TEMP);   // dir (-s, s)
        const float l3 = __fmul_rn(vx, TEMP);                // dir ( 1, 0)
        const float lmax = fmaxf(fmaxf(fabsf(l0), fabsf(l1)),
                                 fmaxf(fabsf(l2), fmaxf(fabsf(l3), 0.f)));
        const float l[9] = {l0, l1, l2, l3, 0.f, -l3, -l2, -l1, -l0};
        float e[9], esum = 0.f;
#pragma unroll
        for (int d = 0; d < 9; ++d) {
            e[d] = __expf(__fsub_rn(l[d], lmax));   // native v_exp_f32
            esum = __fadd_rn(esum, e[d]);
        }
        const float inv = 1.0f / esum;
#pragma unroll
        for (int d = 0; d < 9; ++d) PR[d][s] = __fmul_rn(e[d], inv);

        if (ly >= 1 && ly <= 16 && lx >= 1 && lx <= 32) {          // interior
            const int gidx = (gy0 + ly - 1) * W + gx0 + lx - 1;
            out[3 * HW + gidx] = fnx;
            out[4 * HW + gidx] = fny;
        }
    };
    cell(tid);
    if (tid < 100) cell(tid + 512);
    __syncthreads();

    // ---- phase 3: gather for 16x32 interior (fmaf safe: not amplified) ----
    const int tx = tid & 31, ty = tid >> 5;
    float nm = 0.f, omx = 0.f, omy = 0.f;
#pragma unroll
    for (int d = 0; d < 9; ++d) {
        const int dy = 1 - d / 3, dx = 1 - d % 3;                  // MOVES shift
        const int sn = (ty + 1 + dy) * 36 + (tx + 1 + dx) + 1;
        const float pp = PR[d][sn];
        const float2 pm2 = PM[sn];
        nm  = fmaf(M[sn],  pp, nm);
        omx = fmaf(pm2.x, pp, omx);
        omy = fmaf(pm2.y, pp, omy);
    }
    const int gidx = (gy0 + ty) * W + gx0 + tx;
    out[gidx]          = nm;                                       // unnormalized
    out[HW + gidx]     = omx;
    out[2 * HW + gidx] = omy;

    // ---- block reductions -> line-spread f64 accumulators ----
    float s0 = M[(ty + 1) * 36 + tx + 2];                          // own mass
    float s1 = nm;
#pragma unroll
    for (int off = 32; off > 0; off >>= 1) {
        s0 += __shfl_down(s0, off);
        s1 += __shfl_down(s1, off);
    }
    if ((tid & 63) == 0) { wsum0[tid >> 6] = s0; wsum1[tid >> 6] = s1; }
    __syncthreads();
    if (tid == 0) {
        float t0 = 0.f, t1 = 0.f;
#pragma unroll
        for (int i = 0; i < 8; ++i) { t0 += wsum0[i]; t1 += wsum1[i]; }
        const int slot = (blockIdx.x & (NACC - 1)) * 8;            // own line
        atomicAdd(acc + slot,            (double)t0);
        atomicAdd(acc + NACC * 8 + slot, (double)t1);
    }
}

// ---------------------------------------------------------------------------
// Rescale: reduce the 2*NACC partials in-register (lane-parallel + shuffle),
// then new_mass = mass_tot * new_mass / sum(new_mass), in place, float4.
// ---------------------------------------------------------------------------
__global__ __launch_bounds__(256) void k_norm(
    float* __restrict__ nm, const double* __restrict__ acc)
{
    const int lane = threadIdx.x & 63;
    double s0 = 0.0, s1 = 0.0;
#pragma unroll
    for (int i = 0; i < NACC / 64; ++i) {                // 2 slots per lane
        const int slot = (lane + i * 64) * 8;
        s0 += acc[slot];
        s1 += acc[NACC * 8 + slot];
    }
#pragma unroll
    for (int off = 32; off > 0; off >>= 1) {
        s0 += __shfl_down(s0, off);
        s1 += __shfl_down(s1, off);
    }
    const float mt  = (float)__shfl(s0, 0);
    const float snm = (float)__shfl(s1, 0);

    const int i = (blockIdx.x * 256 + threadIdx.x) * 4;
    float4 v = *(float4*)(nm + i);
    v.x = __fmul_rn(mt, v.x) / snm;
    v.y = __fmul_rn(mt, v.y) / snm;
    v.z = __fmul_rn(mt, v.z) / snm;
    v.w = __fmul_rn(mt, v.w) / snm;
    *(float4*)(nm + i) = v;
}

extern "C" void kernel_launch(void* const* d_in, const int* in_sizes, int n_in,
                              void* d_out, int out_size, void* d_ws, size_t ws_size,
                              hipStream_t stream)
{
    const float* mass  = (const float*)d_in[0];
    const float* mom   = (const float*)d_in[1];
    const float* force = (const float*)d_in[2];
    const float* A     = (const float*)d_in[3];
    const float* ker   = (const float*)d_in[4];
    float* out = (float*)d_out;

    double* acc = (double*)d_ws;                  // 2 * NACC * 8 doubles = 16 KiB
    hipMemsetAsync(acc, 0, 2 * NACC * 8 * sizeof(double), stream);

    k_main<<<dim3(8192), dim3(512), 0, stream>>>(mass, mom, force, A, ker,
                                                 out, acc);
    k_norm<<<dim3(HW / 1024), dim3(256), 0, stream>>>(out, acc);
}